// Round 6
// baseline (153.248 us; speedup 1.0000x reference)
//
#include <hip/hip_runtime.h>
#include <math.h>

#define B 16
#define Q 300
#define T 50
#define NC 80
#define CL 81
#define HH 128
#define WW 128

#define NBLK 512
#define TPB 1024
#define FW 13                    // focal waves per block (wv 0..12)
#define FT (NBLK * FW * 64)      // 425,984 focal threads
#define N4 (B * NC * HH * WW / 4)  // 5,242,880 float4
#define NFULL 12                 // guaranteed iters: 12*FT = 5,111,808 <= N4
#define NCE (NBLK * 2)           // 1024 CE waves
#define NPW NBLK                 // 512 pairs waves

typedef unsigned long long ull;

__device__ __forceinline__ float frcp(float x) { return __builtin_amdgcn_rcpf(x); }

__device__ __forceinline__ float focal_term(float x) {
    float e = __expf(-fabsf(x));             // v_exp_f32
    float ope = 1.0f + e;
    float r = frcp(ope);                     // sigmoid(|x|)
    float sp = fmaxf(x, 0.f) + __logf(ope);  // softplus(x); log arg in (1,2]
    float p = (x >= 0.f) ? r : e * r;        // sigmoid(x)
    return sp * p * p;
}

// pout[block*9 + j]: 0 focal_raw, 1 ce_base, 2 bbox, 3 giou, 4 focal_corr,
//                    5 boxl, 6 npos, 7 ce_num_corr, 8 ce_den_corr

__global__ __launch_bounds__(TPB, 8) void main_kernel(
    const float* __restrict__ pred_logits,
    const float* __restrict__ pred_boxes,
    const float* __restrict__ heatmap,
    const float* __restrict__ box_map,
    const float* __restrict__ tgt_boxes,
    const int* __restrict__ tgt_labels,
    const float* __restrict__ tgt_sizes,
    const int* __restrict__ src_idx,
    const int* __restrict__ tgt_idx,
    const float* __restrict__ ew,
    float* __restrict__ pout) {

    __shared__ float smem[23];
    const int tid = threadIdx.x;
    const int lane = tid & 63;
    const int wv = tid >> 6;

    if (wv < FW) {
        // ---------------- focal baseline (target = 0 everywhere) ----------------
        int fid = blockIdx.x * (FW * 64) + tid;
        const float4* h4 = (const float4*)heatmap;
        float s0 = 0.f, s1 = 0.f;
        #pragma unroll 4
        for (int k = 0; k < NFULL; ++k) {
            float4 v = h4[fid + k * FT];
            s0 += focal_term(v.x) + focal_term(v.y);
            s1 += focal_term(v.z) + focal_term(v.w);
        }
        if (fid < N4 - NFULL * FT) {
            float4 v = h4[fid + NFULL * FT];
            s0 += focal_term(v.x) + focal_term(v.y);
            s1 += focal_term(v.z) + focal_term(v.w);
        }
        float s = s0 + s1;
        #pragma unroll
        for (int off = 32; off; off >>= 1) s += __shfl_xor(s, off);
        if (lane == 0) smem[wv] = s;

    } else if (wv < FW + 2) {
        // ---------------- CE baseline (every row treated as unmatched) ----------------
        int cw = blockIdx.x * 2 + (wv - FW);
        float wNC = ew[NC];
        float num = 0.f;
        for (int r = cw; r < B * Q; r += NCE) {
            const float* row = pred_logits + r * CL;
            float x0 = row[lane];
            float x1 = (lane < CL - 64) ? row[lane + 64] : -INFINITY;
            float m = fmaxf(x0, x1);
            #pragma unroll
            for (int off = 32; off; off >>= 1) m = fmaxf(m, __shfl_xor(m, off));
            float s = __expf(x0 - m) + ((lane < CL - 64) ? __expf(x1 - m) : 0.f);
            #pragma unroll
            for (int off = 32; off; off >>= 1) s += __shfl_xor(s, off);
            float rNC = __shfl(x1, 16);            // row[80] = lane16's x1
            if (lane == 0) num += wNC * ((m + __logf(s)) - rNC);
        }
        if (lane == 0) smem[wv] = num;

    } else {
        // ---------------- pairs: one wave per matched item ----------------
        int pw = blockIdx.x;
        float vals[7] = {0.f, 0.f, 0.f, 0.f, 0.f, 0.f, 0.f};  // lane0-held sums

        for (int i = pw; i < B * T; i += NPW) {
            int b = i / T, t = i % T;
            float inv_h = frcp(tgt_sizes[b * 2 + 0]);
            float inv_w = frcp(tgt_sizes[b * 2 + 1]);

            // lane `l` computes normalized box + cell of target (b, l)
            int lidx = b * T + ((lane < T) ? lane : 0);
            float4 tb = ((const float4*)tgt_boxes)[lidx];
            float ocx = (tb.x + tb.z) * 0.5f * inv_w;
            float ocy = (tb.y + tb.w) * 0.5f * inv_h;
            float ow = (tb.z - tb.x) * inv_w;
            float oh = (tb.w - tb.y) * inv_h;
            int ox = min(max((int)(ocx * WW), 0), WW - 1);
            int oy = min(max((int)(ocy * HH), 0), HH - 1);
            int labl = (lane < T) ? tgt_labels[b * T + lane] : -1;

            int gx = __shfl(ox, t), gy = __shfl(oy, t), lf = __shfl(labl, t);
            float bf0 = __shfl(ocx, t), bf1 = __shfl(ocy, t);
            float bf2 = __shfl(ow, t), bf3 = __shfl(oh, t);

            ull same = __ballot(lane < T && ox == gx && oy == gy);
            ull same_lab = __ballot(lane < T && ox == gx && oy == gy && labl == lf);
            ull below = (1ull << t) - 1ull;
            ull above = ~((1ull << (t + 1)) - 1ull);
            bool first_cell = (same & below) == 0;
            bool last_cell = (same & above) == 0;
            bool first_hm = (same_lab & below) == 0;

            int ti = tgt_idx[b * T + t];
            int qi = src_idx[b * T + t];
            float mt0 = __shfl(ocx, ti), mt1 = __shfl(ocy, ti);
            float mt2 = __shfl(ow, ti), mt3 = __shfl(oh, ti);
            int lab = __shfl(labl, ti);

            // CE correction: lane-parallel logsumexp over row (b*Q+qi)
            const float* row = pred_logits + (b * Q + qi) * CL;
            float x0 = row[lane];
            float x1 = (lane < CL - 64) ? row[lane + 64] : -INFINITY;
            float m = fmaxf(x0, x1);
            #pragma unroll
            for (int off = 32; off; off >>= 1) m = fmaxf(m, __shfl_xor(m, off));
            float se = __expf(x0 - m) + ((lane < CL - 64) ? __expf(x1 - m) : 0.f);
            #pragma unroll
            for (int off = 32; off; off >>= 1) se += __shfl_xor(se, off);
            float lse = m + __logf(se);
            float rlab = (lab < 64) ? __shfl(x0, lab) : __shfl(x1, lab - 64);
            float rNC = __shfl(x1, 16);

            if (lane == 0) {
                float wl = ew[lab], wn = ew[NC];
                vals[5] += wl * (lse - rlab) - wn * (lse - rNC);
                vals[6] += wl - wn;

                if (first_cell) vals[4] += 1.0f;

                if (first_hm) {
                    float x = heatmap[((b * NC + lf) * HH + gy) * WW + gx];
                    float e = __expf(-fabsf(x));
                    float ope = 1.0f + e;
                    float r = frcp(ope);
                    float l1p = __logf(ope);
                    float sp0 = fmaxf(x, 0.f) + l1p;   // softplus(x)
                    float sp1 = sp0 - x;               // softplus(-x)
                    float p = (x >= 0.f) ? r : e * r;
                    float qn = 1.f - p;
                    vals[2] += 0.25f * sp1 * qn * qn - 0.75f * sp0 * p * p;
                }

                if (last_cell) {
                    float bfc[4] = {bf0, bf1, bf2, bf3};
                    float sbl = 0.f;
                    #pragma unroll
                    for (int c = 0; c < 4; ++c)
                        sbl += fabsf(box_map[((b * 4 + c) * HH + gy) * WW + gx] - bfc[c]);
                    vals[3] += sbl;
                }

                // pair L1 + GIoU
                float4 sb = ((const float4*)pred_boxes)[b * Q + qi];
                float s0 = sb.x, s1 = sb.y, s2 = sb.z, s3 = sb.w;
                vals[0] += fabsf(s0 - mt0) + fabsf(s1 - mt1) + fabsf(s2 - mt2) + fabsf(s3 - mt3);

                float a0 = s0 - 0.5f * s2, a1 = s1 - 0.5f * s3;
                float a2 = s0 + 0.5f * s2, a3 = s1 + 0.5f * s3;
                float b0 = mt0 - 0.5f * mt2, b1 = mt1 - 0.5f * mt3;
                float b2 = mt0 + 0.5f * mt2, b3 = mt1 + 0.5f * mt3;
                float area_a = (a2 - a0) * (a3 - a1), area_b = (b2 - b0) * (b3 - b1);
                float iw = fmaxf(fminf(a2, b2) - fmaxf(a0, b0), 0.f);
                float ih = fmaxf(fminf(a3, b3) - fmaxf(a1, b1), 0.f);
                float inter = iw * ih;
                float uni = area_a + area_b - inter;
                float iou = inter / uni;
                float cw_ = fmaxf(fmaxf(a2, b2) - fminf(a0, b0), 0.f);
                float ch_ = fmaxf(fmaxf(a3, b3) - fminf(a1, b1), 0.f);
                float area_c = cw_ * ch_;
                vals[1] += 1.0f - (iou - (area_c - uni) / area_c);
            }
        }

        if (lane == 0)
            for (int j = 0; j < 7; ++j) smem[16 + j] = vals[j];
    }

    __syncthreads();
    if (tid == 0) {
        float f = 0.f;
        #pragma unroll
        for (int w = 0; w < FW; ++w) f += smem[w];
        float* base = pout + blockIdx.x * 9;
        base[0] = f;                      // focal raw (×0.75 in final)
        base[1] = smem[FW] + smem[FW + 1];
        #pragma unroll
        for (int j = 0; j < 7; ++j) base[2 + j] = smem[16 + j];
    }
}

__global__ __launch_bounds__(256) void final_kernel(
    const float* __restrict__ pout, const float* __restrict__ ew,
    float* __restrict__ out) {
    __shared__ float lds[4][9];
    int tid = threadIdx.x;
    int lane = tid & 63, wv = tid >> 6;
    float s[9] = {0.f, 0.f, 0.f, 0.f, 0.f, 0.f, 0.f, 0.f, 0.f};
    for (int b = tid; b < NBLK; b += 256) {
        #pragma unroll
        for (int j = 0; j < 9; ++j) s[j] += pout[b * 9 + j];
    }
    #pragma unroll
    for (int j = 0; j < 9; ++j)
        #pragma unroll
        for (int off = 32; off; off >>= 1) s[j] += __shfl_xor(s[j], off);
    if (lane == 0)
        for (int j = 0; j < 9; ++j) lds[wv][j] = s[j];
    __syncthreads();
    if (tid == 0) {
        float tot[9];
        #pragma unroll
        for (int j = 0; j < 9; ++j)
            tot[j] = lds[0][j] + lds[1][j] + lds[2][j] + lds[3][j];
        float wNC = ew[NC];
        float ce = (tot[1] + tot[7]) / (wNC * (float)(B * Q) + tot[8]);
        float bbox = tot[2] / (float)(B * T);
        float giou = tot[3] / (float)(B * T);
        float npos = fmaxf(tot[6], 1.0f);
        float aux = (0.75f * tot[0] + tot[4]) / npos + 5.0f * (tot[5] / npos);
        out[0] = ce;
        out[1] = bbox;
        out[2] = giou;
        out[3] = aux;
        out[4] = ce + 5.f * bbox + 2.f * giou + aux;
    }
}

extern "C" void kernel_launch(void* const* d_in, const int* in_sizes, int n_in,
                              void* d_out, int out_size, void* d_ws, size_t ws_size,
                              hipStream_t stream) {
    const float* pred_logits    = (const float*)d_in[0];
    const float* pred_boxes     = (const float*)d_in[1];
    const float* heatmap_logits = (const float*)d_in[2];
    const float* box_map        = (const float*)d_in[3];
    const float* tgt_boxes      = (const float*)d_in[4];
    const int*   tgt_labels     = (const int*)d_in[5];
    const float* tgt_sizes      = (const float*)d_in[6];
    const int*   src_idx        = (const int*)d_in[7];
    const int*   tgt_idx        = (const int*)d_in[8];
    const float* empty_weight   = (const float*)d_in[9];
    float* out = (float*)d_out;

    float* pout = (float*)d_ws;

    main_kernel<<<NBLK, TPB, 0, stream>>>(
        pred_logits, pred_boxes, heatmap_logits, box_map, tgt_boxes, tgt_labels,
        tgt_sizes, src_idx, tgt_idx, empty_weight, pout);
    final_kernel<<<1, 256, 0, stream>>>(pout, empty_weight, out);
}

// Round 7
// 145.278 us; speedup vs baseline: 1.0549x; 1.0549x over previous
//
#include <hip/hip_runtime.h>
#include <math.h>

#define B 16
#define Q 300
#define T 50
#define NC 80
#define CL 81
#define HH 128
#define WW 128

#define NBF 1280          // focal blocks: 327,680 threads -> exactly 16 float4/thread
#define NBC 300           // ce blocks (1200 waves, 4 rows each)
#define NBP 100           // pairs blocks (400 waves, 2 items each)
#define NBLK (NBF + NBC + NBP)
#define N4 (B * NC * HH * WW / 4)   // 5,242,880 float4
#define FTH (NBF * 256)             // 327,680 focal threads; N4/FTH = 16 exactly

typedef unsigned long long ull;

__device__ __forceinline__ float frcp(float x) { return __builtin_amdgcn_rcpf(x); }

// ws: pf[NBF] | pce[NBC] | pp[NBP*7]
// pp: 0 bbox, 1 giou, 2 focal_corr, 3 boxl, 4 npos, 5 ce_num_corr, 6 ce_den_corr

__device__ __forceinline__ float focal_term(float x) {
    float e = __expf(-fabsf(x));             // v_exp_f32
    float ope = 1.0f + e;
    float r = frcp(ope);                     // sigmoid(|x|)
    float sp = fmaxf(x, 0.f) + __logf(ope);  // softplus(x); log arg in (1,2]
    float p = (x >= 0.f) ? r : e * r;        // sigmoid(x)
    return sp * p * p;
}

__global__ void main_kernel(
    const float* __restrict__ pred_logits,
    const float* __restrict__ pred_boxes,
    const float* __restrict__ heatmap,
    const float* __restrict__ box_map,
    const float* __restrict__ tgt_boxes,
    const int* __restrict__ tgt_labels,
    const float* __restrict__ tgt_sizes,
    const int* __restrict__ src_idx,
    const int* __restrict__ tgt_idx,
    const float* __restrict__ ew,
    float* __restrict__ pf, float* __restrict__ pce, float* __restrict__ pp) {

    __shared__ float smem[28];
    const int lane = threadIdx.x & 63;
    const int wv = threadIdx.x >> 6;

    if (blockIdx.x < NBF) {
        // ---------------- focal baseline (target = 0 everywhere) ----------------
        // Exactly 16 strides/thread, fully unrolled: compiler can hoist all 16
        // global_load_dwordx4 ahead of the math (max loads in flight, no per-iter wait).
        int fid = blockIdx.x * 256 + threadIdx.x;
        const float4* h4 = (const float4*)heatmap;
        float a0 = 0.f, a1 = 0.f, a2 = 0.f, a3 = 0.f;
        #pragma unroll
        for (int k = 0; k < 16; ++k) {
            float4 v = h4[fid + k * FTH];
            a0 += focal_term(v.x);
            a1 += focal_term(v.y);
            a2 += focal_term(v.z);
            a3 += focal_term(v.w);
        }
        float s = ((a0 + a1) + (a2 + a3)) * 0.75f;
        #pragma unroll
        for (int off = 32; off; off >>= 1) s += __shfl_xor(s, off);
        if (lane == 0) smem[wv] = s;
        __syncthreads();
        if (threadIdx.x == 0)
            pf[blockIdx.x] = smem[0] + smem[1] + smem[2] + smem[3];

    } else if (blockIdx.x < NBF + NBC) {
        // ---------------- CE baseline (every row treated as unmatched) ----------------
        int wave = (blockIdx.x - NBF) * 4 + wv;
        const int NW = NBC * 4;
        float wNC = ew[NC];
        float num = 0.f;
        for (int r = wave; r < B * Q; r += NW) {
            const float* row = pred_logits + r * CL;
            float x0 = row[lane];
            float x1 = (lane < CL - 64) ? row[lane + 64] : -INFINITY;
            float m = fmaxf(x0, x1);
            #pragma unroll
            for (int off = 32; off; off >>= 1) m = fmaxf(m, __shfl_xor(m, off));
            float s = __expf(x0 - m) + ((lane < CL - 64) ? __expf(x1 - m) : 0.f);
            #pragma unroll
            for (int off = 32; off; off >>= 1) s += __shfl_xor(s, off);
            float rNC = __shfl(x1, 16);            // row[80] = lane16's x1
            if (lane == 0) num += wNC * ((m + __logf(s)) - rNC);
        }
        if (lane == 0) smem[wv] = num;
        __syncthreads();
        if (threadIdx.x == 0)
            pce[blockIdx.x - NBF] = smem[0] + smem[1] + smem[2] + smem[3];

    } else {
        // ---------------- pairs: one wave per matched item ----------------
        int pw = (blockIdx.x - NBF - NBC) * 4 + wv;
        const int NW = NBP * 4;
        float vals[7] = {0.f, 0.f, 0.f, 0.f, 0.f, 0.f, 0.f};  // lane0-held sums

        for (int i = pw; i < B * T; i += NW) {
            int b = i / T, t = i % T;
            float inv_h = frcp(tgt_sizes[b * 2 + 0]);
            float inv_w = frcp(tgt_sizes[b * 2 + 1]);

            // lane `l` computes normalized box + cell of target (b, l)
            int lidx = b * T + ((lane < T) ? lane : 0);
            float4 tb = ((const float4*)tgt_boxes)[lidx];
            float ocx = (tb.x + tb.z) * 0.5f * inv_w;
            float ocy = (tb.y + tb.w) * 0.5f * inv_h;
            float ow = (tb.z - tb.x) * inv_w;
            float oh = (tb.w - tb.y) * inv_h;
            int ox = min(max((int)(ocx * WW), 0), WW - 1);
            int oy = min(max((int)(ocy * HH), 0), HH - 1);
            int labl = (lane < T) ? tgt_labels[b * T + lane] : -1;

            int gx = __shfl(ox, t), gy = __shfl(oy, t), lf = __shfl(labl, t);
            float bf0 = __shfl(ocx, t), bf1 = __shfl(ocy, t);
            float bf2 = __shfl(ow, t), bf3 = __shfl(oh, t);

            ull same = __ballot(lane < T && ox == gx && oy == gy);
            ull same_lab = __ballot(lane < T && ox == gx && oy == gy && labl == lf);
            ull below = (1ull << t) - 1ull;
            ull above = ~((1ull << (t + 1)) - 1ull);
            bool first_cell = (same & below) == 0;
            bool last_cell = (same & above) == 0;
            bool first_hm = (same_lab & below) == 0;

            int ti = tgt_idx[b * T + t];
            int qi = src_idx[b * T + t];
            float mt0 = __shfl(ocx, ti), mt1 = __shfl(ocy, ti);
            float mt2 = __shfl(ow, ti), mt3 = __shfl(oh, ti);
            int lab = __shfl(labl, ti);

            // CE correction: lane-parallel logsumexp over row (b*Q+qi)
            const float* row = pred_logits + (b * Q + qi) * CL;
            float x0 = row[lane];
            float x1 = (lane < CL - 64) ? row[lane + 64] : -INFINITY;
            float m = fmaxf(x0, x1);
            #pragma unroll
            for (int off = 32; off; off >>= 1) m = fmaxf(m, __shfl_xor(m, off));
            float se = __expf(x0 - m) + ((lane < CL - 64) ? __expf(x1 - m) : 0.f);
            #pragma unroll
            for (int off = 32; off; off >>= 1) se += __shfl_xor(se, off);
            float lse = m + __logf(se);
            float rlab = (lab < 64) ? __shfl(x0, lab) : __shfl(x1, lab - 64);
            float rNC = __shfl(x1, 16);

            if (lane == 0) {
                float wl = ew[lab], wn = ew[NC];
                vals[5] += wl * (lse - rlab) - wn * (lse - rNC);
                vals[6] += wl - wn;

                if (first_cell) vals[4] += 1.0f;

                if (first_hm) {
                    float x = heatmap[((b * NC + lf) * HH + gy) * WW + gx];
                    float e = __expf(-fabsf(x));
                    float ope = 1.0f + e;
                    float r = frcp(ope);
                    float l1p = __logf(ope);
                    float sp0 = fmaxf(x, 0.f) + l1p;   // softplus(x)
                    float sp1 = sp0 - x;               // softplus(-x)
                    float p = (x >= 0.f) ? r : e * r;
                    float qn = 1.f - p;
                    vals[2] += 0.25f * sp1 * qn * qn - 0.75f * sp0 * p * p;
                }

                if (last_cell) {
                    float bfc[4] = {bf0, bf1, bf2, bf3};
                    float sbl = 0.f;
                    #pragma unroll
                    for (int c = 0; c < 4; ++c)
                        sbl += fabsf(box_map[((b * 4 + c) * HH + gy) * WW + gx] - bfc[c]);
                    vals[3] += sbl;
                }

                // pair L1 + GIoU
                float4 sb = ((const float4*)pred_boxes)[b * Q + qi];
                float s0 = sb.x, s1 = sb.y, s2 = sb.z, s3 = sb.w;
                vals[0] += fabsf(s0 - mt0) + fabsf(s1 - mt1) + fabsf(s2 - mt2) + fabsf(s3 - mt3);

                float a0 = s0 - 0.5f * s2, a1 = s1 - 0.5f * s3;
                float a2 = s0 + 0.5f * s2, a3 = s1 + 0.5f * s3;
                float b0 = mt0 - 0.5f * mt2, b1 = mt1 - 0.5f * mt3;
                float b2 = mt0 + 0.5f * mt2, b3 = mt1 + 0.5f * mt3;
                float area_a = (a2 - a0) * (a3 - a1), area_b = (b2 - b0) * (b3 - b1);
                float iw = fmaxf(fminf(a2, b2) - fmaxf(a0, b0), 0.f);
                float ih = fmaxf(fminf(a3, b3) - fmaxf(a1, b1), 0.f);
                float inter = iw * ih;
                float uni = area_a + area_b - inter;
                float iou = inter / uni;
                float cw_ = fmaxf(fmaxf(a2, b2) - fminf(a0, b0), 0.f);
                float ch_ = fmaxf(fmaxf(a3, b3) - fminf(a1, b1), 0.f);
                float area_c = cw_ * ch_;
                vals[1] += 1.0f - (iou - (area_c - uni) / area_c);
            }
        }

        if (lane == 0)
            for (int j = 0; j < 7; ++j) smem[wv * 7 + j] = vals[j];
        __syncthreads();
        if (threadIdx.x == 0) {
            int blockrel = blockIdx.x - NBF - NBC;
            for (int j = 0; j < 7; ++j)
                pp[blockrel * 7 + j] = smem[j] + smem[7 + j] + smem[14 + j] + smem[21 + j];
        }
    }
}

__global__ __launch_bounds__(256) void final_kernel(
    const float* __restrict__ pf, const float* __restrict__ pce,
    const float* __restrict__ pp, const float* __restrict__ ew,
    float* __restrict__ out) {
    __shared__ float lds[16];
    __shared__ float s7[7];
    int tid = threadIdx.x;
    if (tid < 7) s7[tid] = 0.f;
    __syncthreads();
    float fsum = 0.f;
    for (int i = tid; i < NBF; i += 256) fsum += pf[i];
    float cesum = 0.f;
    for (int i = tid; i < NBC; i += 256) cesum += pce[i];
    #pragma unroll
    for (int off = 32; off; off >>= 1) {
        fsum += __shfl_xor(fsum, off);
        cesum += __shfl_xor(cesum, off);
    }
    for (int i = tid; i < NBP * 7; i += 256) atomicAdd(&s7[i % 7], pp[i]);
    int lane = tid & 63, wv = tid >> 6;
    if (lane == 0) { lds[wv] = fsum; lds[8 + wv] = cesum; }
    __syncthreads();
    if (tid == 0) {
        float focal = lds[0] + lds[1] + lds[2] + lds[3];
        float cen = lds[8] + lds[9] + lds[10] + lds[11];
        float wNC = ew[NC];
        float ce = (cen + s7[5]) / (wNC * (float)(B * Q) + s7[6]);
        float bbox = s7[0] / (float)(B * T);
        float giou = s7[1] / (float)(B * T);
        float npos = fmaxf(s7[4], 1.0f);
        float aux = (focal + s7[2]) / npos + 5.0f * (s7[3] / npos);
        out[0] = ce;
        out[1] = bbox;
        out[2] = giou;
        out[3] = aux;
        out[4] = ce + 5.f * bbox + 2.f * giou + aux;
    }
}

extern "C" void kernel_launch(void* const* d_in, const int* in_sizes, int n_in,
                              void* d_out, int out_size, void* d_ws, size_t ws_size,
                              hipStream_t stream) {
    const float* pred_logits    = (const float*)d_in[0];
    const float* pred_boxes     = (const float*)d_in[1];
    const float* heatmap_logits = (const float*)d_in[2];
    const float* box_map        = (const float*)d_in[3];
    const float* tgt_boxes      = (const float*)d_in[4];
    const int*   tgt_labels     = (const int*)d_in[5];
    const float* tgt_sizes      = (const float*)d_in[6];
    const int*   src_idx        = (const int*)d_in[7];
    const int*   tgt_idx        = (const int*)d_in[8];
    const float* empty_weight   = (const float*)d_in[9];
    float* out = (float*)d_out;

    float* pf  = (float*)d_ws;
    float* pce = pf + NBF;
    float* pp  = pce + NBC;

    main_kernel<<<NBLK, 256, 0, stream>>>(
        pred_logits, pred_boxes, heatmap_logits, box_map, tgt_boxes, tgt_labels,
        tgt_sizes, src_idx, tgt_idx, empty_weight, pf, pce, pp);
    final_kernel<<<1, 256, 0, stream>>>(pf, pce, pp, empty_weight, out);
}